// Round 3
// baseline (367.010 us; speedup 1.0000x reference)
//
#include <hip/hip_runtime.h>
#include <hip/hip_bf16.h>

// KL-style loss: mean_n [ -sum_y target[n,y] * log_softmax(pred)[n,y] ]
// N = 4194304 rows, C = 10, fp32 in, scalar fp32 out.
//
// Identity: loss_total = sum_{n,y} t[n,y] * (lse_n - x[n,y])
// R2 established: pattern/occupancy-invariant plateau at ~2.7 TB/s read.
// R3: non-temporal loads (no-allocate streaming policy) + unconstrained
// VGPR budget so all 10 dwordx4 loads stay in flight per thread.

#define N_ROWS 4194304
#define C_DIM 10
#define BLOCK 256
#define ROWS_PER_BLOCK 512                        // 2 rows per thread
#define WORDS_PER_BLOCK (ROWS_PER_BLOCK * C_DIM)  // 5120 floats per array
#define F4_PER_THREAD 5                           // 5120/4/256
#define LDS_PAD 513                               // column pad: bank=(y+r)%32

typedef float v4f __attribute__((ext_vector_type(4)));  // native vector for nt builtin

__global__ void kl_loss_kernel(
    const float* __restrict__ pred,
    const float* __restrict__ tgt,
    float* __restrict__ out)
{
    __shared__ float sp[C_DIM][LDS_PAD];     // pred tile, column-major sp[y][r]
    __shared__ float slse[ROWS_PER_BLOCK];   // per-row logsumexp
    __shared__ float sred[BLOCK / 64];       // final block reduction

    const int tid = threadIdx.x;
    const size_t blk_f4 = (size_t)blockIdx.x * (WORDS_PER_BLOCK / 4);

    const v4f* p4 = reinterpret_cast<const v4f*>(pred);
    const v4f* t4 = reinterpret_cast<const v4f*>(tgt);

    // ---- Phase 1: coalesced non-temporal loads, all 10 issued up front ----
    v4f pv[F4_PER_THREAD], tv[F4_PER_THREAD];
#pragma unroll
    for (int i = 0; i < F4_PER_THREAD; ++i)
        pv[i] = __builtin_nontemporal_load(&p4[blk_f4 + i * BLOCK + tid]);
#pragma unroll
    for (int i = 0; i < F4_PER_THREAD; ++i)
        tv[i] = __builtin_nontemporal_load(&t4[blk_f4 + i * BLOCK + tid]);

    // scatter pred into column-major LDS
#pragma unroll
    for (int i = 0; i < F4_PER_THREAD; ++i) {
        int w = (i * BLOCK + tid) * 4;          // word offset in block tile
        int r = w / C_DIM;
        int y = w - r * C_DIM;
#pragma unroll
        for (int c = 0; c < 4; ++c) {
            sp[y][r] = pv[i][c];
            ++y;
            if (y == C_DIM) { y = 0; ++r; }
        }
    }
    __syncthreads();

    // ---- Phase 2: per-row logsumexp (conflict-free column reads) ----
#pragma unroll
    for (int half = 0; half < 2; ++half) {
        int r = tid + half * BLOCK;
        float x[C_DIM];
#pragma unroll
        for (int y = 0; y < C_DIM; ++y) x[y] = sp[y][r];
        float m = x[0];
#pragma unroll
        for (int y = 1; y < C_DIM; ++y) m = fmaxf(m, x[y]);
        float s = 0.0f;
#pragma unroll
        for (int y = 0; y < C_DIM; ++y) s += __expf(x[y] - m);
        slse[r] = m + __logf(s);
    }
    __syncthreads();

    // ---- Phase 3: elementwise t*(lse - x) from registers ----
    float acc = 0.0f;
#pragma unroll
    for (int i = 0; i < F4_PER_THREAD; ++i) {
        int w = (i * BLOCK + tid) * 4;
        int r = w / C_DIM;
        int y = w - r * C_DIM;
#pragma unroll
        for (int c = 0; c < 4; ++c) {
            acc = fmaf(tv[i][c], slse[r] - pv[i][c], acc);
            ++y;
            if (y == C_DIM) { y = 0; ++r; }
        }
    }

    // ---- Reduction: wave shuffle -> LDS -> one atomic per block ----
#pragma unroll
    for (int off = 32; off > 0; off >>= 1)
        acc += __shfl_down(acc, off, 64);

    const int lane = tid & 63;
    const int wid  = tid >> 6;
    if (lane == 0) sred[wid] = acc;
    __syncthreads();

    if (tid == 0) {
        float b = sred[0] + sred[1] + sred[2] + sred[3];
        atomicAdd(out, b * (1.0f / (float)N_ROWS));
    }
}

extern "C" void kernel_launch(void* const* d_in, const int* in_sizes, int n_in,
                              void* d_out, int out_size, void* d_ws, size_t ws_size,
                              hipStream_t stream)
{
    const float* pred = (const float*)d_in[0];
    const float* tgt  = (const float*)d_in[1];
    float* out = (float*)d_out;

    // d_out is poisoned (0xAA) before every call; zero it for the atomic accumulate.
    hipMemsetAsync(out, 0, sizeof(float), stream);

    const int blocks = N_ROWS / ROWS_PER_BLOCK;   // 8192
    kl_loss_kernel<<<blocks, BLOCK, 0, stream>>>(pred, tgt, out);
}

// Round 4
// 309.707 us; speedup vs baseline: 1.1850x; 1.1850x over previous
//
#include <hip/hip_runtime.h>
#include <hip/hip_bf16.h>

// KL-style loss: mean_n [ -sum_y target[n,y] * log_softmax(pred)[n,y] ]
// N = 4194304 rows, C = 10, fp32 in, scalar fp32 out.
//
// R0-R3 finding: 117-126 us plateau invariant to access pattern/occupancy/
// cache policy. Common factor: 8192 same-address atomicAdds (WRITE_SIZE=256KB
// = 8192 x 32B write-throughs). 8192 x ~35cyc same-line RMW turnaround
// ~= 119 us == the plateau. R4: per-block partials to d_ws + tiny reduce
// kernel; zero contended atomics.

#define N_ROWS 4194304
#define C_DIM 10
#define BLOCK 256
#define ROWS_PER_BLOCK 512                        // 2 rows per thread
#define WORDS_PER_BLOCK (ROWS_PER_BLOCK * C_DIM)  // 5120 floats per array
#define F4_PER_THREAD 5                           // 5120/4/256
#define LDS_PAD 513                               // column pad: bank=(y+r)%32
#define NBLOCKS (N_ROWS / ROWS_PER_BLOCK)         // 8192

typedef float v4f __attribute__((ext_vector_type(4)));

// ---------------- main kernel: per-block partial sum ----------------
template <bool USE_ATOMIC>
__global__ void kl_loss_kernel(
    const float* __restrict__ pred,
    const float* __restrict__ tgt,
    float* __restrict__ partial)   // NBLOCKS floats (or d_out if USE_ATOMIC)
{
    __shared__ float sp[C_DIM][LDS_PAD];     // pred tile, column-major sp[y][r]
    __shared__ float slse[ROWS_PER_BLOCK];   // per-row logsumexp
    __shared__ float sred[BLOCK / 64];

    const int tid = threadIdx.x;
    const size_t blk_f4 = (size_t)blockIdx.x * (WORDS_PER_BLOCK / 4);

    const v4f* p4 = reinterpret_cast<const v4f*>(pred);
    const v4f* t4 = reinterpret_cast<const v4f*>(tgt);

    // ---- Phase 1: coalesced non-temporal loads ----
    v4f pv[F4_PER_THREAD], tv[F4_PER_THREAD];
#pragma unroll
    for (int i = 0; i < F4_PER_THREAD; ++i)
        pv[i] = __builtin_nontemporal_load(&p4[blk_f4 + i * BLOCK + tid]);
#pragma unroll
    for (int i = 0; i < F4_PER_THREAD; ++i)
        tv[i] = __builtin_nontemporal_load(&t4[blk_f4 + i * BLOCK + tid]);

    // scatter pred into column-major LDS
#pragma unroll
    for (int i = 0; i < F4_PER_THREAD; ++i) {
        int w = (i * BLOCK + tid) * 4;
        int r = w / C_DIM;
        int y = w - r * C_DIM;
#pragma unroll
        for (int c = 0; c < 4; ++c) {
            sp[y][r] = pv[i][c];
            ++y;
            if (y == C_DIM) { y = 0; ++r; }
        }
    }
    __syncthreads();

    // ---- Phase 2: per-row logsumexp (conflict-free column reads) ----
#pragma unroll
    for (int half = 0; half < 2; ++half) {
        int r = tid + half * BLOCK;
        float x[C_DIM];
#pragma unroll
        for (int y = 0; y < C_DIM; ++y) x[y] = sp[y][r];
        float m = x[0];
#pragma unroll
        for (int y = 1; y < C_DIM; ++y) m = fmaxf(m, x[y]);
        float s = 0.0f;
#pragma unroll
        for (int y = 0; y < C_DIM; ++y) s += __expf(x[y] - m);
        slse[r] = m + __logf(s);
    }
    __syncthreads();

    // ---- Phase 3: elementwise t*(lse - x) from registers ----
    float acc = 0.0f;
#pragma unroll
    for (int i = 0; i < F4_PER_THREAD; ++i) {
        int w = (i * BLOCK + tid) * 4;
        int r = w / C_DIM;
        int y = w - r * C_DIM;
#pragma unroll
        for (int c = 0; c < 4; ++c) {
            acc = fmaf(tv[i][c], slse[r] - pv[i][c], acc);
            ++y;
            if (y == C_DIM) { y = 0; ++r; }
        }
    }

    // ---- Reduction: wave shuffle -> LDS -> one value per block ----
#pragma unroll
    for (int off = 32; off > 0; off >>= 1)
        acc += __shfl_down(acc, off, 64);

    const int lane = tid & 63;
    const int wid  = tid >> 6;
    if (lane == 0) sred[wid] = acc;
    __syncthreads();

    if (tid == 0) {
        float b = sred[0] + sred[1] + sred[2] + sred[3];
        if (USE_ATOMIC)
            atomicAdd(partial, b * (1.0f / (float)N_ROWS));
        else
            partial[blockIdx.x] = b;   // distinct address per block: no contention
    }
}

// ---------------- final reduce: one block over NBLOCKS partials ----------------
__global__ __launch_bounds__(BLOCK) void kl_reduce_kernel(
    const float* __restrict__ partial,
    float* __restrict__ out)
{
    __shared__ float sred[BLOCK / 64];
    const int tid = threadIdx.x;

    float acc = 0.0f;
    for (int i = tid; i < NBLOCKS; i += BLOCK)
        acc += partial[i];

#pragma unroll
    for (int off = 32; off > 0; off >>= 1)
        acc += __shfl_down(acc, off, 64);

    const int lane = tid & 63;
    const int wid  = tid >> 6;
    if (lane == 0) sred[wid] = acc;
    __syncthreads();

    if (tid == 0) {
        float b = sred[0] + sred[1] + sred[2] + sred[3];
        out[0] = b * (1.0f / (float)N_ROWS);   // plain store; no memset needed
    }
}

extern "C" void kernel_launch(void* const* d_in, const int* in_sizes, int n_in,
                              void* d_out, int out_size, void* d_ws, size_t ws_size,
                              hipStream_t stream)
{
    const float* pred = (const float*)d_in[0];
    const float* tgt  = (const float*)d_in[1];
    float* out = (float*)d_out;

    if (ws_size >= NBLOCKS * sizeof(float)) {
        float* partial = (float*)d_ws;
        kl_loss_kernel<false><<<NBLOCKS, BLOCK, 0, stream>>>(pred, tgt, partial);
        kl_reduce_kernel<<<1, BLOCK, 0, stream>>>(partial, out);
    } else {
        // fallback: contended-atomic path (R3 behavior)
        hipMemsetAsync(out, 0, sizeof(float), stream);
        kl_loss_kernel<true><<<NBLOCKS, BLOCK, 0, stream>>>(pred, tgt, out);
    }
}

// Round 5
// 302.041 us; speedup vs baseline: 1.2151x; 1.0254x over previous
//
#include <hip/hip_runtime.h>
#include <hip/hip_bf16.h>

// KL-style loss: mean_n [ -sum_y target[n,y] * log_softmax(pred)[n,y] ]
// N = 4194304 rows, C = 10, fp32 in, scalar fp32 out.
//
// R4 finding: contended atomic removed -> kernel fell below harness fill ops
// (~60 us inferred vs ~50 us stream floor). R5: algebraic split
//   loss_total = sum_n st_n*lse_n - sum_{n,y} t*x
// dot term computed from registers (no row structure); st via reusing the
// single LDS pred buffer; lse/st stay in registers -> no slse array, no
// per-element magic-div chain in an epilogue phase.

#define N_ROWS 4194304
#define C_DIM 10
#define BLOCK 256
#define ROWS_PER_BLOCK 512                        // 2 rows per thread
#define WORDS_PER_BLOCK (ROWS_PER_BLOCK * C_DIM)  // 5120 floats per array
#define F4_PER_THREAD 5                           // 5120/4/256
#define LDS_PAD 513                               // column pad: bank=(y*17+r)%32
#define NBLOCKS (N_ROWS / ROWS_PER_BLOCK)         // 8192
#define RBLOCK 1024

typedef float v4f __attribute__((ext_vector_type(4)));

__global__ void kl_loss_kernel(
    const float* __restrict__ pred,
    const float* __restrict__ tgt,
    float* __restrict__ partial)   // NBLOCKS floats
{
    __shared__ float sp[C_DIM][LDS_PAD];   // one tile buffer, reused pred->tgt
    __shared__ float sred[BLOCK / 64];

    const int tid = threadIdx.x;
    const size_t blk_f4 = (size_t)blockIdx.x * (WORDS_PER_BLOCK / 4);

    const v4f* p4 = reinterpret_cast<const v4f*>(pred);
    const v4f* t4 = reinterpret_cast<const v4f*>(tgt);

    // ---- Phase 1: coalesced non-temporal loads ----
    v4f pv[F4_PER_THREAD], tv[F4_PER_THREAD];
#pragma unroll
    for (int i = 0; i < F4_PER_THREAD; ++i)
        pv[i] = __builtin_nontemporal_load(&p4[blk_f4 + i * BLOCK + tid]);
#pragma unroll
    for (int i = 0; i < F4_PER_THREAD; ++i)
        tv[i] = __builtin_nontemporal_load(&t4[blk_f4 + i * BLOCK + tid]);

    // global dot term: no row structure needed
    float dot = 0.0f;
#pragma unroll
    for (int i = 0; i < F4_PER_THREAD; ++i)
#pragma unroll
        for (int c = 0; c < 4; ++c)
            dot = fmaf(tv[i][c], pv[i][c], dot);

    // ---- Phase 2: scatter pred column-major, lse for rows tid, tid+256 ----
#pragma unroll
    for (int i = 0; i < F4_PER_THREAD; ++i) {
        int w = (i * BLOCK + tid) * 4;
        int r = w / C_DIM;
        int y = w - r * C_DIM;
#pragma unroll
        for (int c = 0; c < 4; ++c) {
            sp[y][r] = pv[i][c];
            ++y;
            if (y == C_DIM) { y = 0; ++r; }
        }
    }
    __syncthreads();

    float lse[2];
#pragma unroll
    for (int half = 0; half < 2; ++half) {
        const int r = tid + half * BLOCK;
        float x[C_DIM];
#pragma unroll
        for (int y = 0; y < C_DIM; ++y) x[y] = sp[y][r];
        float m = x[0];
#pragma unroll
        for (int y = 1; y < C_DIM; ++y) m = fmaxf(m, x[y]);
        float s = 0.0f;
#pragma unroll
        for (int y = 0; y < C_DIM; ++y) s += __expf(x[y] - m);
        lse[half] = m + __logf(s);
    }
    __syncthreads();   // all pred-column reads done before overwrite

    // ---- Phase 3: scatter tgt into the SAME buffer, st for same rows ----
#pragma unroll
    for (int i = 0; i < F4_PER_THREAD; ++i) {
        int w = (i * BLOCK + tid) * 4;
        int r = w / C_DIM;
        int y = w - r * C_DIM;
#pragma unroll
        for (int c = 0; c < 4; ++c) {
            sp[y][r] = tv[i][c];
            ++y;
            if (y == C_DIM) { y = 0; ++r; }
        }
    }
    __syncthreads();

    float acc = -dot;
#pragma unroll
    for (int half = 0; half < 2; ++half) {
        const int r = tid + half * BLOCK;
        float st = 0.0f;
#pragma unroll
        for (int y = 0; y < C_DIM; ++y) st += sp[y][r];
        acc = fmaf(st, lse[half], acc);
    }

    // ---- Reduction: wave shuffle -> LDS -> one store per block ----
#pragma unroll
    for (int off = 32; off > 0; off >>= 1)
        acc += __shfl_down(acc, off, 64);

    const int lane = tid & 63;
    const int wid  = tid >> 6;
    if (lane == 0) sred[wid] = acc;
    __syncthreads();

    if (tid == 0)
        partial[blockIdx.x] = sred[0] + sred[1] + sred[2] + sred[3];
}

// ---------------- final reduce: one block over NBLOCKS partials ----------------
__global__ __launch_bounds__(RBLOCK) void kl_reduce_kernel(
    const float* __restrict__ partial,
    float* __restrict__ out)
{
    __shared__ float sred[RBLOCK / 64];
    const int tid = threadIdx.x;

    float acc = 0.0f;
#pragma unroll
    for (int i = 0; i < NBLOCKS / RBLOCK; ++i)
        acc += partial[i * RBLOCK + tid];

#pragma unroll
    for (int off = 32; off > 0; off >>= 1)
        acc += __shfl_down(acc, off, 64);

    const int lane = tid & 63;
    const int wid  = tid >> 6;
    if (lane == 0) sred[wid] = acc;
    __syncthreads();

    if (tid == 0) {
        float b = 0.0f;
#pragma unroll
        for (int i = 0; i < RBLOCK / 64; ++i) b += sred[i];
        out[0] = b * (1.0f / (float)N_ROWS);
    }
}

extern "C" void kernel_launch(void* const* d_in, const int* in_sizes, int n_in,
                              void* d_out, int out_size, void* d_ws, size_t ws_size,
                              hipStream_t stream)
{
    const float* pred = (const float*)d_in[0];
    const float* tgt  = (const float*)d_in[1];
    float* out = (float*)d_out;
    float* partialbuf = (float*)d_ws;   // ws_size >> 32 KB per R4 profile

    kl_loss_kernel<<<NBLOCKS, BLOCK, 0, stream>>>(pred, tgt, partialbuf);
    kl_reduce_kernel<<<1, RBLOCK, 0, stream>>>(partialbuf, out);
}